// Round 7
// baseline (275.453 us; speedup 1.0000x reference)
//
#include <hip/hip_runtime.h>
#include <stdint.h>

typedef unsigned short u16;
typedef __attribute__((ext_vector_type(8))) short bf16x8;
typedef __attribute__((ext_vector_type(8))) unsigned short u16x8;
typedef __attribute__((ext_vector_type(4))) float f32x4;

#define S_LEN 2048
#define EDIM 1024
#define NH 16
#define HD 64

static __device__ __forceinline__ u16 f2bf(float f) {
  union { float f; uint32_t u; } v; v.f = f;
  uint32_t r = v.u + 0x7fffu + ((v.u >> 16) & 1u);  // RNE
  return (u16)(r >> 16);
}

// packed f32x2 -> bf16x2 (RNE), low=a high=b (validated by v8 run)
static __device__ __forceinline__ uint32_t cvtpk_bf16(float a, float b) {
  uint32_t r;
  asm("v_cvt_pk_bf16_f32 %0, %1, %2" : "=v"(r) : "v"(a), "v"(b));
  return r;
}

// async global->LDS, 16B per lane; LDS dest = wave-uniform base + lane*16
static __device__ __forceinline__ void gload_lds16(const u16* g, u16* l) {
  __builtin_amdgcn_global_load_lds(
      (const __attribute__((address_space(1))) void*)g,
      (__attribute__((address_space(3))) void*)l, 16, 0, 0);
}

// pinned 16B global load (used for Q prologue only)
static __device__ __forceinline__ bf16x8 gload16(const u16* p) {
  bf16x8 r;
  asm volatile("global_load_dwordx4 %0, %1, off" : "=v"(r) : "v"(p));
  return r;
}

// counted wait + full scheduling fence (rule #18)
#define WAIT_VM(n)                                   \
  do {                                               \
    asm volatile("s_waitcnt vmcnt(" #n ")");         \
    __builtin_amdgcn_sched_barrier(0);               \
  } while (0)

#define BARRIER()                                    \
  do {                                               \
    __builtin_amdgcn_s_barrier();                    \
    __builtin_amdgcn_sched_barrier(0);               \
  } while (0)

// ---------------------------------------------------------------------------
// pack v3: x fp32->bf16 vectorized; W transposes via LDS 64x64 tiles.
// NEW: Wq is pre-scaled by D^-0.5*log2(e) so attention scores come out of
// the QKV GEMM ready for exp2 (removes 32 mul + 32 sub per attn tile).
// Blocks: [0,8192) x-convert; [8192,8960) wqkv; [8960,9216) wproj.
// ---------------------------------------------------------------------------
__global__ __launch_bounds__(256) void pack_inputs(
    const float* __restrict__ x, const float* __restrict__ Wq,
    const float* __restrict__ Wk, const float* __restrict__ Wv,
    const float* __restrict__ Wp,
    u16* __restrict__ xb, u16* __restrict__ wqkvT, u16* __restrict__ wprojT) {
  const int blk = blockIdx.x;
  const int tid = threadIdx.x;
  if (blk < 8192) {
    int idx = blk * 256 + tid;  // 2,097,152 float4 groups total
    float4 v = ((const float4*)x)[idx];
    ushort4 o;
    o.x = f2bf(v.x); o.y = f2bf(v.y); o.z = f2bf(v.z); o.w = f2bf(v.w);
    ((ushort4*)xb)[idx] = o;
    return;
  }
  __shared__ u16 tile[64][65];  // +1 pad: gather phase 2-way banked (free)
  const float* src;
  size_t src_rs;   // src row stride (floats)
  u16* dst;        // dst tile base: dst + r*1024 + c
  float wscale = 1.0f;
  if (blk < 8960) {
    int t = blk - 8192;          // 0..767
    int mh = t >> 4;             // 0..47
    int et = t & 15;             // e-tile
    int m = mh >> 4, h = mh & 15;
    const float* W = (m == 0) ? Wq : (m == 1) ? Wk : Wv;
    if (m == 0) wscale = 0.1803368801111204f;  // D^-0.5 * log2(e)
    src = W + ((size_t)(h * EDIM + et * 64)) * HD;
    src_rs = HD;
    dst = wqkvT + (size_t)(m * 1024 + h * 64) * 1024 + et * 64;
  } else {
    int t = blk - 8960;          // 0..255
    int kt = t >> 4, nt = t & 15;
    src = Wp + (size_t)(kt * 64) * 1024 + nt * 64;
    src_rs = 1024;
    dst = wprojT + (size_t)(nt * 64) * 1024 + kt * 64;
  }
  {
    const int rr = tid >> 4;        // 0..15
    const int c4 = (tid & 15) << 2; // 0..60
#pragma unroll
    for (int p = 0; p < 4; p++) {
      const int r = p * 16 + rr;
      float4 v = *(const float4*)(src + (size_t)r * src_rs + c4);
      tile[r][c4 + 0] = f2bf(v.x * wscale);
      tile[r][c4 + 1] = f2bf(v.y * wscale);
      tile[r][c4 + 2] = f2bf(v.z * wscale);
      tile[r][c4 + 3] = f2bf(v.w * wscale);
    }
  }
  __syncthreads();
  {
    const int rr = tid >> 3;        // 0..31
    const int c8 = (tid & 7) << 3;  // 0..56
#pragma unroll
    for (int p = 0; p < 2; p++) {
      const int r = p * 32 + rr;    // out row (= src col)
      u16x8 o;
#pragma unroll
      for (int j = 0; j < 8; j++) o[j] = tile[c8 + j][r];
      *(u16x8*)(dst + (size_t)r * 1024 + c8) = o;
    }
  }
}

// ---------------------------------------------------------------------------
// 128x128-tile bf16 MFMA GEMM, BK=64:  C[M,N] = A[M,K] @ Bt[N,K]^T.
// (unchanged from round 5 — BK=64 + slot-XOR swizzle)
// ---------------------------------------------------------------------------
template <int EPI>
__global__ __launch_bounds__(256) void gemm128(
    const u16* __restrict__ A, const u16* __restrict__ Bt,
    const float* __restrict__ bias,
    u16* __restrict__ o0, u16* __restrict__ o1, u16* __restrict__ o2,
    float* __restrict__ of, int K, int N) {
  __shared__ __align__(16) u16 As[128 * 64];  // 16 KB, linear dest (lds-dma)
  __shared__ __align__(16) u16 Bs[128 * 64];
  const int tid  = threadIdx.x;
  const int lane = tid & 63;
  const int wave = tid >> 6;
  const int wm = wave >> 1;
  const int wn = wave & 1;
  const int col = lane & 15;
  const int quad = lane >> 4;
  const int cs = col & 7;
  const int m0 = blockIdx.y << 7;
  const int n0 = blockIdx.x << 7;

  const int srow  = lane >> 3;
  const int sslot = (lane & 7) ^ srow;
  const u16* gA = A + (size_t)(m0 + (wave << 5) + srow) * K + sslot * 8;
  const u16* gB = Bt + (size_t)(n0 + (wave << 5) + srow) * K + sslot * 8;
  u16* lA = &As[(wave << 5) << 6];
  u16* lB = &Bs[(wave << 5) << 6];

  f32x4 acc[4][4];
#pragma unroll
  for (int i = 0; i < 4; i++)
#pragma unroll
    for (int j = 0; j < 4; j++) acc[i][j] = (f32x4){0.f, 0.f, 0.f, 0.f};

  for (int kk = 0; kk < K; kk += 64) {
    __syncthreads();
#pragma unroll
    for (int i = 0; i < 4; i++) {
      gload_lds16(gA + (size_t)(i * 8) * K + kk, lA + i * 512);
      gload_lds16(gB + (size_t)(i * 8) * K + kk, lB + i * 512);
    }
    __syncthreads();

#pragma unroll
    for (int x = 0; x < 2; x++) {  // k-halves: k = x*32 + quad*8
      bf16x8 af[4], bfr[4];
#pragma unroll
      for (int i = 0; i < 4; i++)
        af[i] = *(const bf16x8*)(
            &As[((wm * 64 + i * 16 + col) << 6) + ((((x << 2) + quad) ^ cs) << 3)]);
#pragma unroll
      for (int j = 0; j < 4; j++)
        bfr[j] = *(const bf16x8*)(
            &Bs[((wn * 64 + j * 16 + col) << 6) + ((((x << 2) + quad) ^ cs) << 3)]);
#pragma unroll
      for (int i = 0; i < 4; i++)
#pragma unroll
        for (int j = 0; j < 4; j++)
          acc[i][j] = __builtin_amdgcn_mfma_f32_16x16x32_bf16(af[i], bfr[j],
                                                              acc[i][j], 0, 0, 0);
    }
  }

#pragma unroll
  for (int i = 0; i < 4; i++) {
#pragma unroll
    for (int j = 0; j < 4; j++) {
      // C/D layout: col=lane&15, row=quad*4+reg  [m89-verified]
      const int rg0 = m0 + wm * 64 + i * 16 + quad * 4;
      const int cg = n0 + wn * 64 + j * 16 + col;
      if (EPI == 0) {
        const int mat = cg >> 10;
        const int rem = cg & 1023;
        const int h = rem >> 6;
        const int d = rem & 63;
        const int b = rg0 >> 11;
        const int s0 = rg0 & 2047;
        if (mat == 2) {
          ushort4 o;
          o.x = f2bf(acc[i][j][0]); o.y = f2bf(acc[i][j][1]);
          o.z = f2bf(acc[i][j][2]); o.w = f2bf(acc[i][j][3]);
          *(ushort4*)(&o2[(((size_t)(b * NH + h) * HD + d) << 11) + s0]) = o;
        } else {
          u16* dst = (mat == 0) ? o0 : o1;
#pragma unroll
          for (int r = 0; r < 4; r++)
            dst[((size_t)((b * NH + h) * S_LEN + s0 + r) << 6) + d] =
                f2bf(acc[i][j][r]);
        }
      } else {
#pragma unroll
        for (int r = 0; r < 4; r++)
          of[(size_t)(rg0 + r) * N + cg] = acc[i][j][r] + bias[cg];
      }
    }
  }
}

// ---------------------------------------------------------------------------
// Fused causal flash attention v9 — v7 dataflow, 8-wave blocks.
// v9 vs v7: (1) 8 waves (256 q rows) share one K/V staging -> 512 blocks,
// ALL co-resident (2/CU), 4 waves/SIMD (was 2.2 — the measured stall);
// qb folded so gid and gid+256 sum to qb=7 -> per-CU work balanced.
// (2) Ps is single-a, streamed (a=0 convert+write+PV, then a=1) -> LDS
// stays 51,200B. (3) softmax = exp2(s) only: scale pre-folded into Wq,
// -C2 dropped (cancels in p/sum(p)); bf16 convert via cvt_pk pairs+shr
// (numerics validated by v8). VALU/tile ~1712 -> ~1300 issue-cycles.
// v8's ds_bpermute path REVERTED (4.3M bank conflicts, regression).
// ---------------------------------------------------------------------------
__global__ __launch_bounds__(512, 4) void attn_fused(
    const u16* __restrict__ Q, const u16* __restrict__ K,
    const u16* __restrict__ Vt, u16* __restrict__ O) {
  __shared__ __align__(16) u16 Kbuf[2][64 * 64];  // [kv row][64 halves] swz
  __shared__ __align__(16) u16 Vbuf[2][64 * 64];  // [d row][64 halves] swz
  __shared__ __align__(16) u16 Ps[8][16 * 72];    // per-wave, single-a

  const int tid  = threadIdx.x;
  const int lane = tid & 63;
  const int wave = tid >> 6;
  const int col  = lane & 15;
  const int quad = lane >> 4;
  const int cs   = col & 7;
  const int gid  = blockIdx.x;
  const int bh = ((gid & 7) << 3) | ((gid >> 3) & 7);  // 8 bh per XCD
  const int hi = gid >> 6;                             // 0..7
  const int qb = (hi < 4) ? (7 - hi) : (hi - 4);       // folded: balanced CUs
  const int b = bh >> 4;
  const int h = bh & 15;
  const int q0w = qb * 256 + wave * 32;                // wave's q base

  const u16* Kbh = K + (size_t)bh * S_LEN * HD;
  const u16* Vbh = Vt + (size_t)bh * HD * S_LEN;

  // staging lane constants: wave stages 8 K rows + 8 V rows (1 instr each)
  const int srow  = lane >> 3;                  // 0..7
  const int sslot = (lane & 7) ^ srow;          // 0..7 (inverse swizzle)
  const int r0 = wave * 8;                      // this wave's 8 rows

  // Q fragments (once per block); Wq pre-scaled, so scores are exp2-ready
  bf16x8 qf[2][2];
#pragma unroll
  for (int a = 0; a < 2; a++) {
    const u16* Qrow = Q + ((size_t)bh * S_LEN + q0w + a * 16 + col) * HD;
    qf[a][0] = gload16(Qrow + quad * 8);
    qf[a][1] = gload16(Qrow + 32 + quad * 8);
  }

  f32x4 oacc[2][4];
#pragma unroll
  for (int a = 0; a < 2; a++)
#pragma unroll
    for (int n = 0; n < 4; n++) oacc[a][n] = (f32x4){0.f, 0.f, 0.f, 0.f};
  float lrow[2][4] = {{0.f, 0.f, 0.f, 0.f}, {0.f, 0.f, 0.f, 0.f}};

  auto STAGE = [&](int buf, int kv0) {
    gload_lds16(Kbh + (size_t)(kv0 + r0 + srow) * HD + sslot * 8,
                &Kbuf[buf][r0 * 64]);
    gload_lds16(Vbh + (size_t)(r0 + srow) * S_LEN + kv0 + sslot * 8,
                &Vbuf[buf][r0 * 64]);
  };

  const int T = 4 * qb + 4;  // block covers kv tiles 0..T-1
  int cur = 0;
  STAGE(0, 0);
  WAIT_VM(0);  // Q + first tile resident
  BARRIER();

  for (int t = 0; t < T; t++) {
    const int kv0 = t << 6;
    if (t + 1 < T) STAGE(cur ^ 1, kv0 + 64);

    if (kv0 <= q0w + 31) {  // wave-uniform: tile intersects causal range
      // --- QK^T from swizzled Kbuf (scores pre-scaled for exp2) ----------
      f32x4 sc[2][4];
#pragma unroll
      for (int j = 0; j < 4; j++) {
        const u16* kr = &Kbuf[cur][(j * 16 + col) * 64];
        const bf16x8 kf0 = *(const bf16x8*)(kr + ((quad ^ cs) << 3));
        const bf16x8 kf1 = *(const bf16x8*)(kr + (((4 + quad) ^ cs) << 3));
#pragma unroll
        for (int a = 0; a < 2; a++) {
          sc[a][j] = (f32x4){0.f, 0.f, 0.f, 0.f};
          sc[a][j] = __builtin_amdgcn_mfma_f32_16x16x32_bf16(qf[a][0], kf0, sc[a][j], 0, 0, 0);
          sc[a][j] = __builtin_amdgcn_mfma_f32_16x16x32_bf16(qf[a][1], kf1, sc[a][j], 0, 0, 0);
        }
      }

      const bool diag = (kv0 + 63 > q0w);
      // --- stream a: softmax -> Ps -> PV (single Ps buffer reused) -------
#pragma unroll
      for (int a = 0; a < 2; a++) {
#pragma unroll
        for (int r = 0; r < 4; r++) {
          float p[4];
#pragma unroll
          for (int j = 0; j < 4; j++) {
            float v = exp2f(sc[a][j][r]);  // unnormalized; 2^-C2 cancels
            if (diag) {
              const int ql = q0w - kv0 + a * 16 + quad * 4 + r;
              if (j * 16 + col > ql) v = 0.f;
            }
            lrow[a][r] += v;
            p[j] = v;
          }
          const uint32_t pk0 = cvtpk_bf16(p[0], p[1]);
          const uint32_t pk1 = cvtpk_bf16(p[2], p[3]);
          u16* row = &Ps[wave][(quad * 4 + r) * 72 + col];
          row[0]  = (u16)pk0;
          row[16] = (u16)(pk0 >> 16);
          row[32] = (u16)pk1;
          row[48] = (u16)(pk1 >> 16);
        }
        const bf16x8 pf0 = *(const bf16x8*)(&Ps[wave][col * 72 + quad * 8]);
        const bf16x8 pf1 = *(const bf16x8*)(&Ps[wave][col * 72 + 32 + quad * 8]);
#pragma unroll
        for (int n = 0; n < 4; n++) {
          const u16* vr = &Vbuf[cur][(n * 16 + col) * 64];
          const bf16x8 vf0 = *(const bf16x8*)(vr + ((quad ^ cs) << 3));
          const bf16x8 vf1 = *(const bf16x8*)(vr + (((4 + quad) ^ cs) << 3));
          oacc[a][n] = __builtin_amdgcn_mfma_f32_16x16x32_bf16(pf0, vf0, oacc[a][n], 0, 0, 0);
          oacc[a][n] = __builtin_amdgcn_mfma_f32_16x16x32_bf16(pf1, vf1, oacc[a][n], 0, 0, 0);
        }
      }
    }

    WAIT_VM(0);  // next tile's staging (issued above) has landed
    BARRIER();   // all waves done reading cur; next tile visible to all
    cur ^= 1;
  }

#pragma unroll
  for (int a = 0; a < 2; a++)
#pragma unroll
    for (int r = 0; r < 4; r++) {
      float l = lrow[a][r];
#pragma unroll
      for (int off = 1; off < 16; off <<= 1) l += __shfl_xor(l, off);
      const float inv = 1.0f / l;
      const size_t row = (size_t)b * S_LEN + q0w + a * 16 + quad * 4 + r;
#pragma unroll
      for (int n = 0; n < 4; n++)
        O[row * EDIM + h * HD + n * 16 + col] = f2bf(oacc[a][n][r] * inv);
    }
}

// ---------------------------------------------------------------------------
extern "C" void kernel_launch(void* const* d_in, const int* in_sizes, int n_in,
                              void* d_out, int out_size, void* d_ws, size_t ws_size,
                              hipStream_t stream) {
  const float* x  = (const float*)d_in[0];
  const float* Wq = (const float*)d_in[1];
  const float* Wk = (const float*)d_in[2];
  const float* Wv = (const float*)d_in[3];
  const float* Wp = (const float*)d_in[4];
  const float* bp = (const float*)d_in[5];
  float* out = (float*)d_out;

  char* ws = (char*)d_ws;
  u16* wqkvT  = (u16*)(ws);              //  6,291,456 B  [3072][1024] bf16
  u16* wprojT = (u16*)(ws + 6291456);    //  2,097,152 B  [1024][1024] bf16
  u16* Qb     = (u16*)(ws + 8388608);    // 16,777,216 B  [B,H,S,D] bf16
  u16* Kb     = (u16*)(ws + 25165824);   // 16,777,216 B  [B,H,S,D] bf16
  u16* Vtb    = (u16*)(ws + 41943040);   // 16,777,216 B  [B,H,D,S] bf16
  u16* xb     = (u16*)(ws + 58720256);   // 16,777,216 B  [B*S][E] bf16
  u16* Ob     = xb;                      // aliases xb (dead after QKV GEMM)

  pack_inputs<<<dim3(9216), dim3(256), 0, stream>>>(x, Wq, Wk, Wv, Wp,
                                                    xb, wqkvT, wprojT);
  gemm128<0><<<dim3(24, 64), dim3(256), 0, stream>>>(
      xb, wqkvT, (const float*)nullptr, Qb, Kb, Vtb, (float*)nullptr, 1024, 3072);
  attn_fused<<<dim3(512), dim3(512), 0, stream>>>(Qb, Kb, Vtb, Ob);
  gemm128<1><<<dim3(8, 64), dim3(256), 0, stream>>>(
      Ob, wprojT, bp, (u16*)nullptr, (u16*)nullptr, (u16*)nullptr, out, 1024, 1024);
}

// Round 8
// 268.233 us; speedup vs baseline: 1.0269x; 1.0269x over previous
//
#include <hip/hip_runtime.h>
#include <stdint.h>

typedef unsigned short u16;
typedef __attribute__((ext_vector_type(8))) short bf16x8;
typedef __attribute__((ext_vector_type(8))) unsigned short u16x8;
typedef __attribute__((ext_vector_type(4))) float f32x4;

#define S_LEN 2048
#define EDIM 1024
#define NH 16
#define HD 64

static __device__ __forceinline__ u16 f2bf(float f) {
  union { float f; uint32_t u; } v; v.f = f;
  uint32_t r = v.u + 0x7fffu + ((v.u >> 16) & 1u);  // RNE
  return (u16)(r >> 16);
}

// packed f32x2 -> bf16x2 (RNE), low=a high=b (validated by v8/v9 runs)
static __device__ __forceinline__ uint32_t cvtpk_bf16(float a, float b) {
  uint32_t r;
  asm("v_cvt_pk_bf16_f32 %0, %1, %2" : "=v"(r) : "v"(a), "v"(b));
  return r;
}

// async global->LDS, 16B per lane; LDS dest = wave-uniform base + lane*16
static __device__ __forceinline__ void gload_lds16(const u16* g, u16* l) {
  __builtin_amdgcn_global_load_lds(
      (const __attribute__((address_space(1))) void*)g,
      (__attribute__((address_space(3))) void*)l, 16, 0, 0);
}

// pinned 16B global load (used for Q prologue only)
static __device__ __forceinline__ bf16x8 gload16(const u16* p) {
  bf16x8 r;
  asm volatile("global_load_dwordx4 %0, %1, off" : "=v"(r) : "v"(p));
  return r;
}

// counted wait + full scheduling fence (rule #18)
#define WAIT_VM(n)                                   \
  do {                                               \
    asm volatile("s_waitcnt vmcnt(" #n ")");         \
    __builtin_amdgcn_sched_barrier(0);               \
  } while (0)

#define BARRIER()                                    \
  do {                                               \
    __builtin_amdgcn_s_barrier();                    \
    __builtin_amdgcn_sched_barrier(0);               \
  } while (0)

// ---------------------------------------------------------------------------
// pack v3: x fp32->bf16 vectorized; W transposes via LDS 64x64 tiles.
// Wq is pre-scaled by D^-0.5*log2(e) so attention scores come out of the
// QKV GEMM ready for exp2 (removes 32 v_fma per attn tile).  [v9-validated]
// Blocks: [0,8192) x-convert; [8192,8960) wqkv; [8960,9216) wproj.
// ---------------------------------------------------------------------------
__global__ __launch_bounds__(256) void pack_inputs(
    const float* __restrict__ x, const float* __restrict__ Wq,
    const float* __restrict__ Wk, const float* __restrict__ Wv,
    const float* __restrict__ Wp,
    u16* __restrict__ xb, u16* __restrict__ wqkvT, u16* __restrict__ wprojT) {
  const int blk = blockIdx.x;
  const int tid = threadIdx.x;
  if (blk < 8192) {
    int idx = blk * 256 + tid;  // 2,097,152 float4 groups total
    float4 v = ((const float4*)x)[idx];
    ushort4 o;
    o.x = f2bf(v.x); o.y = f2bf(v.y); o.z = f2bf(v.z); o.w = f2bf(v.w);
    ((ushort4*)xb)[idx] = o;
    return;
  }
  __shared__ u16 tile[64][65];  // +1 pad: gather phase 2-way banked (free)
  const float* src;
  size_t src_rs;   // src row stride (floats)
  u16* dst;        // dst tile base: dst + r*1024 + c
  float wscale = 1.0f;
  if (blk < 8960) {
    int t = blk - 8192;          // 0..767
    int mh = t >> 4;             // 0..47
    int et = t & 15;             // e-tile
    int m = mh >> 4, h = mh & 15;
    const float* W = (m == 0) ? Wq : (m == 1) ? Wk : Wv;
    if (m == 0) wscale = 0.1803368801111204f;  // D^-0.5 * log2(e)
    src = W + ((size_t)(h * EDIM + et * 64)) * HD;
    src_rs = HD;
    dst = wqkvT + (size_t)(m * 1024 + h * 64) * 1024 + et * 64;
  } else {
    int t = blk - 8960;          // 0..255
    int kt = t >> 4, nt = t & 15;
    src = Wp + (size_t)(kt * 64) * 1024 + nt * 64;
    src_rs = 1024;
    dst = wprojT + (size_t)(nt * 64) * 1024 + kt * 64;
  }
  {
    const int rr = tid >> 4;        // 0..15
    const int c4 = (tid & 15) << 2; // 0..60
#pragma unroll
    for (int p = 0; p < 4; p++) {
      const int r = p * 16 + rr;
      float4 v = *(const float4*)(src + (size_t)r * src_rs + c4);
      tile[r][c4 + 0] = f2bf(v.x * wscale);
      tile[r][c4 + 1] = f2bf(v.y * wscale);
      tile[r][c4 + 2] = f2bf(v.z * wscale);
      tile[r][c4 + 3] = f2bf(v.w * wscale);
    }
  }
  __syncthreads();
  {
    const int rr = tid >> 3;        // 0..31
    const int c8 = (tid & 7) << 3;  // 0..56
#pragma unroll
    for (int p = 0; p < 2; p++) {
      const int r = p * 32 + rr;    // out row (= src col)
      u16x8 o;
#pragma unroll
      for (int j = 0; j < 8; j++) o[j] = tile[c8 + j][r];
      *(u16x8*)(dst + (size_t)r * 1024 + c8) = o;
    }
  }
}

// ---------------------------------------------------------------------------
// 128x128-tile bf16 MFMA GEMM, BK=64:  C[M,N] = A[M,K] @ Bt[N,K]^T.
// (unchanged from round 5 — BK=64 + slot-XOR swizzle)
// ---------------------------------------------------------------------------
template <int EPI>
__global__ __launch_bounds__(256) void gemm128(
    const u16* __restrict__ A, const u16* __restrict__ Bt,
    const float* __restrict__ bias,
    u16* __restrict__ o0, u16* __restrict__ o1, u16* __restrict__ o2,
    float* __restrict__ of, int K, int N) {
  __shared__ __align__(16) u16 As[128 * 64];  // 16 KB, linear dest (lds-dma)
  __shared__ __align__(16) u16 Bs[128 * 64];
  const int tid  = threadIdx.x;
  const int lane = tid & 63;
  const int wave = tid >> 6;
  const int wm = wave >> 1;
  const int wn = wave & 1;
  const int col = lane & 15;
  const int quad = lane >> 4;
  const int cs = col & 7;
  const int m0 = blockIdx.y << 7;
  const int n0 = blockIdx.x << 7;

  const int srow  = lane >> 3;
  const int sslot = (lane & 7) ^ srow;
  const u16* gA = A + (size_t)(m0 + (wave << 5) + srow) * K + sslot * 8;
  const u16* gB = Bt + (size_t)(n0 + (wave << 5) + srow) * K + sslot * 8;
  u16* lA = &As[(wave << 5) << 6];
  u16* lB = &Bs[(wave << 5) << 6];

  f32x4 acc[4][4];
#pragma unroll
  for (int i = 0; i < 4; i++)
#pragma unroll
    for (int j = 0; j < 4; j++) acc[i][j] = (f32x4){0.f, 0.f, 0.f, 0.f};

  for (int kk = 0; kk < K; kk += 64) {
    __syncthreads();
#pragma unroll
    for (int i = 0; i < 4; i++) {
      gload_lds16(gA + (size_t)(i * 8) * K + kk, lA + i * 512);
      gload_lds16(gB + (size_t)(i * 8) * K + kk, lB + i * 512);
    }
    __syncthreads();

#pragma unroll
    for (int x = 0; x < 2; x++) {  // k-halves: k = x*32 + quad*8
      bf16x8 af[4], bfr[4];
#pragma unroll
      for (int i = 0; i < 4; i++)
        af[i] = *(const bf16x8*)(
            &As[((wm * 64 + i * 16 + col) << 6) + ((((x << 2) + quad) ^ cs) << 3)]);
#pragma unroll
      for (int j = 0; j < 4; j++)
        bfr[j] = *(const bf16x8*)(
            &Bs[((wn * 64 + j * 16 + col) << 6) + ((((x << 2) + quad) ^ cs) << 3)]);
#pragma unroll
      for (int i = 0; i < 4; i++)
#pragma unroll
        for (int j = 0; j < 4; j++)
          acc[i][j] = __builtin_amdgcn_mfma_f32_16x16x32_bf16(af[i], bfr[j],
                                                              acc[i][j], 0, 0, 0);
    }
  }

#pragma unroll
  for (int i = 0; i < 4; i++) {
#pragma unroll
    for (int j = 0; j < 4; j++) {
      // C/D layout: col=lane&15, row=quad*4+reg  [m89-verified]
      const int rg0 = m0 + wm * 64 + i * 16 + quad * 4;
      const int cg = n0 + wn * 64 + j * 16 + col;
      if (EPI == 0) {
        const int mat = cg >> 10;
        const int rem = cg & 1023;
        const int h = rem >> 6;
        const int d = rem & 63;
        const int b = rg0 >> 11;
        const int s0 = rg0 & 2047;
        if (mat == 2) {
          ushort4 o;
          o.x = f2bf(acc[i][j][0]); o.y = f2bf(acc[i][j][1]);
          o.z = f2bf(acc[i][j][2]); o.w = f2bf(acc[i][j][3]);
          *(ushort4*)(&o2[(((size_t)(b * NH + h) * HD + d) << 11) + s0]) = o;
        } else {
          u16* dst = (mat == 0) ? o0 : o1;
#pragma unroll
          for (int r = 0; r < 4; r++)
            dst[((size_t)((b * NH + h) * S_LEN + s0 + r) << 6) + d] =
                f2bf(acc[i][j][r]);
        }
      } else {
#pragma unroll
        for (int r = 0; r < 4; r++)
          of[(size_t)(rg0 + r) * N + cg] = acc[i][j][r] + bias[cg];
      }
    }
  }
}

// ---------------------------------------------------------------------------
// Fused causal flash attention v10 — v7 structure (measured 79.2us), with
// ONLY the v9-validated VALU cuts applied to the softmax inner loop:
//   (1) scores arrive pre-scaled (Wq folded: D^-0.5*log2e) -> no v_fma
//   (2) p = exp2(s) unnormalized; the 2^-C2 constant cancels in p/sum(p)
//   (3) P->bf16 via v_cvt_pk_bf16_f32 pairs (+shr) instead of 4xf2bf ops
// ~190 of ~390 VALU instr per wave-tile removed on a 59.6%-VALUBusy kernel.
// Structure (4-wave/128q blocks, 1024-block grid, dbuf K/V staging, Ps
// two-a layout, PV, epilogue) is byte-identical to v7. v8's shfl path and
// v9's 8-wave blocks both REVERTED (measured regressions).
// ---------------------------------------------------------------------------
__global__ __launch_bounds__(256, 3) void attn_fused(
    const u16* __restrict__ Q, const u16* __restrict__ K,
    const u16* __restrict__ Vt, u16* __restrict__ O) {
  __shared__ __align__(16) u16 Kbuf[2][64 * 64];  // [kv row][64 halves] swz
  __shared__ __align__(16) u16 Vbuf[2][64 * 64];  // [d row][64 halves] swz
  __shared__ __align__(16) u16 Ps[4][2][16 * 72];

  const int tid  = threadIdx.x;
  const int lane = tid & 63;
  const int wave = tid >> 6;
  const int col  = lane & 15;
  const int quad = lane >> 4;
  const int cs   = col & 7;
  const int gid  = blockIdx.x;
  const int bh = ((gid & 7) << 3) | ((gid >> 3) & 7);  // 8 bh per XCD
  const int qb = 15 - (gid >> 6);                      // heavy-first
  const int b = bh >> 4;
  const int h = bh & 15;
  const int q0w = qb * 128 + wave * 32;                // wave's q base

  const u16* Kbh = K + (size_t)bh * S_LEN * HD;
  const u16* Vbh = Vt + (size_t)bh * HD * S_LEN;

  // staging lane constants: instr covers 8 rows; lane L -> row r0+(L>>3),
  // 16B slot (L&7); source slot = (L&7) ^ (row&7)  [inverse swizzle]
  const int srow  = lane >> 3;                  // 0..7
  const int sslot = (lane & 7) ^ srow;          // 0..7
  const int r0a = wave * 16;
  const int r0b = wave * 16 + 8;

  // Q fragments (once per block); Wq pre-scaled, so scores are exp2-ready
  bf16x8 qf[2][2];
#pragma unroll
  for (int a = 0; a < 2; a++) {
    const u16* Qrow = Q + ((size_t)bh * S_LEN + q0w + a * 16 + col) * HD;
    qf[a][0] = gload16(Qrow + quad * 8);
    qf[a][1] = gload16(Qrow + 32 + quad * 8);
  }

  f32x4 oacc[2][4];
#pragma unroll
  for (int a = 0; a < 2; a++)
#pragma unroll
    for (int n = 0; n < 4; n++) oacc[a][n] = (f32x4){0.f, 0.f, 0.f, 0.f};
  float lrow[2][4] = {{0.f, 0.f, 0.f, 0.f}, {0.f, 0.f, 0.f, 0.f}};

  auto STAGE = [&](int buf, int kv0) {
    gload_lds16(Kbh + (size_t)(kv0 + r0a + srow) * HD + sslot * 8,
                &Kbuf[buf][r0a * 64]);
    gload_lds16(Kbh + (size_t)(kv0 + r0b + srow) * HD + sslot * 8,
                &Kbuf[buf][r0b * 64]);
    gload_lds16(Vbh + (size_t)(r0a + srow) * S_LEN + kv0 + sslot * 8,
                &Vbuf[buf][r0a * 64]);
    gload_lds16(Vbh + (size_t)(r0b + srow) * S_LEN + kv0 + sslot * 8,
                &Vbuf[buf][r0b * 64]);
  };

  const int T = 2 * qb + 2;  // block covers kv tiles 0..T-1
  int cur = 0;
  STAGE(0, 0);
  WAIT_VM(0);  // Q + first tile resident
  BARRIER();

  for (int t = 0; t < T; t++) {
    const int kv0 = t << 6;
    if (t + 1 < T) STAGE(cur ^ 1, kv0 + 64);

    if (kv0 <= q0w + 31) {  // wave-uniform: this tile intersects causal range
      // --- QK^T from swizzled Kbuf (scores pre-scaled for exp2) ----------
      f32x4 sc[2][4];
#pragma unroll
      for (int j = 0; j < 4; j++) {
        const u16* kr = &Kbuf[cur][(j * 16 + col) * 64];
        const bf16x8 kf0 = *(const bf16x8*)(kr + ((quad ^ cs) << 3));
        const bf16x8 kf1 = *(const bf16x8*)(kr + (((4 + quad) ^ cs) << 3));
#pragma unroll
        for (int a = 0; a < 2; a++) {
          sc[a][j] = (f32x4){0.f, 0.f, 0.f, 0.f};
          sc[a][j] = __builtin_amdgcn_mfma_f32_16x16x32_bf16(qf[a][0], kf0, sc[a][j], 0, 0, 0);
          sc[a][j] = __builtin_amdgcn_mfma_f32_16x16x32_bf16(qf[a][1], kf1, sc[a][j], 0, 0, 0);
        }
      }

      // --- softmax: p = exp2(s) (unnormalized), cvt_pk bf16 pack --------
      const bool diag = (kv0 + 63 > q0w);
#pragma unroll
      for (int a = 0; a < 2; a++)
#pragma unroll
        for (int r = 0; r < 4; r++) {
          float p[4];
#pragma unroll
          for (int j = 0; j < 4; j++) {
            float v = exp2f(sc[a][j][r]);  // 2^-C2 cancels in p/sum(p)
            if (diag) {
              const int ql = q0w - kv0 + a * 16 + quad * 4 + r;
              if (j * 16 + col > ql) v = 0.f;
            }
            lrow[a][r] += v;
            p[j] = v;
          }
          const uint32_t pk0 = cvtpk_bf16(p[0], p[1]);
          const uint32_t pk1 = cvtpk_bf16(p[2], p[3]);
          u16* row = &Ps[wave][a][(quad * 4 + r) * 72 + col];
          row[0]  = (u16)pk0;
          row[16] = (u16)(pk0 >> 16);
          row[32] = (u16)pk1;
          row[48] = (u16)(pk1 >> 16);
        }
      bf16x8 pf[2][2];
#pragma unroll
      for (int a = 0; a < 2; a++) {
        pf[a][0] = *(const bf16x8*)(&Ps[wave][a][col * 72 + quad * 8]);
        pf[a][1] = *(const bf16x8*)(&Ps[wave][a][col * 72 + 32 + quad * 8]);
      }

      // --- PV from swizzled Vbuf ------------------------------------------
#pragma unroll
      for (int n = 0; n < 4; n++) {
        const u16* vr = &Vbuf[cur][(n * 16 + col) * 64];
        const bf16x8 vf0 = *(const bf16x8*)(vr + ((quad ^ cs) << 3));
        const bf16x8 vf1 = *(const bf16x8*)(vr + (((4 + quad) ^ cs) << 3));
#pragma unroll
        for (int a = 0; a < 2; a++) {
          oacc[a][n] = __builtin_amdgcn_mfma_f32_16x16x32_bf16(pf[a][0], vf0, oacc[a][n], 0, 0, 0);
          oacc[a][n] = __builtin_amdgcn_mfma_f32_16x16x32_bf16(pf[a][1], vf1, oacc[a][n], 0, 0, 0);
        }
      }
    }

    WAIT_VM(0);  // next tile's staging (issued above) has landed
    BARRIER();   // all waves done reading cur; next tile visible to all
    cur ^= 1;
  }

#pragma unroll
  for (int a = 0; a < 2; a++)
#pragma unroll
    for (int r = 0; r < 4; r++) {
      float l = lrow[a][r];
#pragma unroll
      for (int off = 1; off < 16; off <<= 1) l += __shfl_xor(l, off);
      const float inv = 1.0f / l;
      const size_t row = (size_t)b * S_LEN + q0w + a * 16 + quad * 4 + r;
#pragma unroll
      for (int n = 0; n < 4; n++)
        O[row * EDIM + h * HD + n * 16 + col] = f2bf(oacc[a][n][r] * inv);
    }
}

// ---------------------------------------------------------------------------
extern "C" void kernel_launch(void* const* d_in, const int* in_sizes, int n_in,
                              void* d_out, int out_size, void* d_ws, size_t ws_size,
                              hipStream_t stream) {
  const float* x  = (const float*)d_in[0];
  const float* Wq = (const float*)d_in[1];
  const float* Wk = (const float*)d_in[2];
  const float* Wv = (const float*)d_in[3];
  const float* Wp = (const float*)d_in[4];
  const float* bp = (const float*)d_in[5];
  float* out = (float*)d_out;

  char* ws = (char*)d_ws;
  u16* wqkvT  = (u16*)(ws);              //  6,291,456 B  [3072][1024] bf16
  u16* wprojT = (u16*)(ws + 6291456);    //  2,097,152 B  [1024][1024] bf16
  u16* Qb     = (u16*)(ws + 8388608);    // 16,777,216 B  [B,H,S,D] bf16
  u16* Kb     = (u16*)(ws + 25165824);   // 16,777,216 B  [B,H,S,D] bf16
  u16* Vtb    = (u16*)(ws + 41943040);   // 16,777,216 B  [B,H,D,S] bf16
  u16* xb     = (u16*)(ws + 58720256);   // 16,777,216 B  [B*S][E] bf16
  u16* Ob     = xb;                      // aliases xb (dead after QKV GEMM)

  pack_inputs<<<dim3(9216), dim3(256), 0, stream>>>(x, Wq, Wk, Wv, Wp,
                                                    xb, wqkvT, wprojT);
  gemm128<0><<<dim3(24, 64), dim3(256), 0, stream>>>(
      xb, wqkvT, (const float*)nullptr, Qb, Kb, Vtb, (float*)nullptr, 1024, 3072);
  attn_fused<<<dim3(1024), dim3(256), 0, stream>>>(Qb, Kb, Vtb, Ob);
  gemm128<1><<<dim3(8, 64), dim3(256), 0, stream>>>(
      Ob, wprojT, bp, (u16*)nullptr, (u16*)nullptr, (u16*)nullptr, out, 1024, 1024);
}

// Round 9
// 267.443 us; speedup vs baseline: 1.0300x; 1.0030x over previous
//
#include <hip/hip_runtime.h>
#include <stdint.h>

typedef unsigned short u16;
typedef __attribute__((ext_vector_type(8))) short bf16x8;
typedef __attribute__((ext_vector_type(8))) unsigned short u16x8;
typedef __attribute__((ext_vector_type(4))) float f32x4;
typedef __attribute__((ext_vector_type(16))) float f32x16;

#define S_LEN 2048
#define EDIM 1024
#define NH 16
#define HD 64

static __device__ __forceinline__ u16 f2bf(float f) {
  union { float f; uint32_t u; } v; v.f = f;
  uint32_t r = v.u + 0x7fffu + ((v.u >> 16) & 1u);  // RNE
  return (u16)(r >> 16);
}

// packed f32x2 -> bf16x2 (RNE), low=a high=b (validated by v8/v9/v10 runs)
static __device__ __forceinline__ uint32_t cvtpk_bf16(float a, float b) {
  uint32_t r;
  asm("v_cvt_pk_bf16_f32 %0, %1, %2" : "=v"(r) : "v"(a), "v"(b));
  return r;
}

// async global->LDS, 16B per lane; LDS dest = wave-uniform base + lane*16
static __device__ __forceinline__ void gload_lds16(const u16* g, u16* l) {
  __builtin_amdgcn_global_load_lds(
      (const __attribute__((address_space(1))) void*)g,
      (__attribute__((address_space(3))) void*)l, 16, 0, 0);
}

// pinned 16B global load (used for Q prologue only)
static __device__ __forceinline__ bf16x8 gload16(const u16* p) {
  bf16x8 r;
  asm volatile("global_load_dwordx4 %0, %1, off" : "=v"(r) : "v"(p));
  return r;
}

// counted wait + full scheduling fence (rule #18)
#define WAIT_VM(n)                                   \
  do {                                               \
    asm volatile("s_waitcnt vmcnt(" #n ")");         \
    __builtin_amdgcn_sched_barrier(0);               \
  } while (0)

#define BARRIER()                                    \
  do {                                               \
    __builtin_amdgcn_s_barrier();                    \
    __builtin_amdgcn_sched_barrier(0);               \
  } while (0)

// ---------------------------------------------------------------------------
// pack v3: x fp32->bf16 vectorized; W transposes via LDS 64x64 tiles.
// Wq pre-scaled by D^-0.5*log2(e): scores come out of QKV GEMM exp2-ready.
// Blocks: [0,8192) x-convert; [8192,8960) wqkv; [8960,9216) wproj.
// ---------------------------------------------------------------------------
__global__ __launch_bounds__(256) void pack_inputs(
    const float* __restrict__ x, const float* __restrict__ Wq,
    const float* __restrict__ Wk, const float* __restrict__ Wv,
    const float* __restrict__ Wp,
    u16* __restrict__ xb, u16* __restrict__ wqkvT, u16* __restrict__ wprojT) {
  const int blk = blockIdx.x;
  const int tid = threadIdx.x;
  if (blk < 8192) {
    int idx = blk * 256 + tid;  // 2,097,152 float4 groups total
    float4 v = ((const float4*)x)[idx];
    ushort4 o;
    o.x = f2bf(v.x); o.y = f2bf(v.y); o.z = f2bf(v.z); o.w = f2bf(v.w);
    ((ushort4*)xb)[idx] = o;
    return;
  }
  __shared__ u16 tile[64][65];  // +1 pad: gather phase 2-way banked (free)
  const float* src;
  size_t src_rs;   // src row stride (floats)
  u16* dst;        // dst tile base: dst + r*1024 + c
  float wscale = 1.0f;
  if (blk < 8960) {
    int t = blk - 8192;          // 0..767
    int mh = t >> 4;             // 0..47
    int et = t & 15;             // e-tile
    int m = mh >> 4, h = mh & 15;
    const float* W = (m == 0) ? Wq : (m == 1) ? Wk : Wv;
    if (m == 0) wscale = 0.1803368801111204f;  // D^-0.5 * log2(e)
    src = W + ((size_t)(h * EDIM + et * 64)) * HD;
    src_rs = HD;
    dst = wqkvT + (size_t)(m * 1024 + h * 64) * 1024 + et * 64;
  } else {
    int t = blk - 8960;          // 0..255
    int kt = t >> 4, nt = t & 15;
    src = Wp + (size_t)(kt * 64) * 1024 + nt * 64;
    src_rs = 1024;
    dst = wprojT + (size_t)(nt * 64) * 1024 + kt * 64;
  }
  {
    const int rr = tid >> 4;        // 0..15
    const int c4 = (tid & 15) << 2; // 0..60
#pragma unroll
    for (int p = 0; p < 4; p++) {
      const int r = p * 16 + rr;
      float4 v = *(const float4*)(src + (size_t)r * src_rs + c4);
      tile[r][c4 + 0] = f2bf(v.x * wscale);
      tile[r][c4 + 1] = f2bf(v.y * wscale);
      tile[r][c4 + 2] = f2bf(v.z * wscale);
      tile[r][c4 + 3] = f2bf(v.w * wscale);
    }
  }
  __syncthreads();
  {
    const int rr = tid >> 3;        // 0..31
    const int c8 = (tid & 7) << 3;  // 0..56
#pragma unroll
    for (int p = 0; p < 2; p++) {
      const int r = p * 32 + rr;    // out row (= src col)
      u16x8 o;
#pragma unroll
      for (int j = 0; j < 8; j++) o[j] = tile[c8 + j][r];
      *(u16x8*)(dst + (size_t)r * 1024 + c8) = o;
    }
  }
}

// ---------------------------------------------------------------------------
// 128x128-tile bf16 MFMA GEMM, BK=64:  C[M,N] = A[M,K] @ Bt[N,K]^T.
// (unchanged from round 5 — BK=64 + slot-XOR swizzle)
// ---------------------------------------------------------------------------
template <int EPI>
__global__ __launch_bounds__(256) void gemm128(
    const u16* __restrict__ A, const u16* __restrict__ Bt,
    const float* __restrict__ bias,
    u16* __restrict__ o0, u16* __restrict__ o1, u16* __restrict__ o2,
    float* __restrict__ of, int K, int N) {
  __shared__ __align__(16) u16 As[128 * 64];  // 16 KB, linear dest (lds-dma)
  __shared__ __align__(16) u16 Bs[128 * 64];
  const int tid  = threadIdx.x;
  const int lane = tid & 63;
  const int wave = tid >> 6;
  const int wm = wave >> 1;
  const int wn = wave & 1;
  const int col = lane & 15;
  const int quad = lane >> 4;
  const int cs = col & 7;
  const int m0 = blockIdx.y << 7;
  const int n0 = blockIdx.x << 7;

  const int srow  = lane >> 3;
  const int sslot = (lane & 7) ^ srow;
  const u16* gA = A + (size_t)(m0 + (wave << 5) + srow) * K + sslot * 8;
  const u16* gB = Bt + (size_t)(n0 + (wave << 5) + srow) * K + sslot * 8;
  u16* lA = &As[(wave << 5) << 6];
  u16* lB = &Bs[(wave << 5) << 6];

  f32x4 acc[4][4];
#pragma unroll
  for (int i = 0; i < 4; i++)
#pragma unroll
    for (int j = 0; j < 4; j++) acc[i][j] = (f32x4){0.f, 0.f, 0.f, 0.f};

  for (int kk = 0; kk < K; kk += 64) {
    __syncthreads();
#pragma unroll
    for (int i = 0; i < 4; i++) {
      gload_lds16(gA + (size_t)(i * 8) * K + kk, lA + i * 512);
      gload_lds16(gB + (size_t)(i * 8) * K + kk, lB + i * 512);
    }
    __syncthreads();

#pragma unroll
    for (int x = 0; x < 2; x++) {  // k-halves: k = x*32 + quad*8
      bf16x8 af[4], bfr[4];
#pragma unroll
      for (int i = 0; i < 4; i++)
        af[i] = *(const bf16x8*)(
            &As[((wm * 64 + i * 16 + col) << 6) + ((((x << 2) + quad) ^ cs) << 3)]);
#pragma unroll
      for (int j = 0; j < 4; j++)
        bfr[j] = *(const bf16x8*)(
            &Bs[((wn * 64 + j * 16 + col) << 6) + ((((x << 2) + quad) ^ cs) << 3)]);
#pragma unroll
      for (int i = 0; i < 4; i++)
#pragma unroll
        for (int j = 0; j < 4; j++)
          acc[i][j] = __builtin_amdgcn_mfma_f32_16x16x32_bf16(af[i], bfr[j],
                                                              acc[i][j], 0, 0, 0);
    }
  }

#pragma unroll
  for (int i = 0; i < 4; i++) {
#pragma unroll
    for (int j = 0; j < 4; j++) {
      // C/D layout: col=lane&15, row=quad*4+reg  [m89-verified]
      const int rg0 = m0 + wm * 64 + i * 16 + quad * 4;
      const int cg = n0 + wn * 64 + j * 16 + col;
      if (EPI == 0) {
        const int mat = cg >> 10;
        const int rem = cg & 1023;
        const int h = rem >> 6;
        const int d = rem & 63;
        const int b = rg0 >> 11;
        const int s0 = rg0 & 2047;
        if (mat == 2) {
          ushort4 o;
          o.x = f2bf(acc[i][j][0]); o.y = f2bf(acc[i][j][1]);
          o.z = f2bf(acc[i][j][2]); o.w = f2bf(acc[i][j][3]);
          *(ushort4*)(&o2[(((size_t)(b * NH + h) * HD + d) << 11) + s0]) = o;
        } else {
          u16* dst = (mat == 0) ? o0 : o1;
#pragma unroll
          for (int r = 0; r < 4; r++)
            dst[((size_t)((b * NH + h) * S_LEN + s0 + r) << 6) + d] =
                f2bf(acc[i][j][r]);
        }
      } else {
#pragma unroll
        for (int r = 0; r < 4; r++)
          of[(size_t)(rg0 + r) * N + cg] = acc[i][j][r] + bias[cg];
      }
    }
  }
}

// ---------------------------------------------------------------------------
// Fused causal flash attention v11 — 32x32 MFMA, swapped operands, P fully
// in-register (T12 structure). Same 4-wave/128q blocks, staging, swizzle,
// barriers and grid as v7/v10 (isolation: one structural change).
//   QK^T: S^T = mfma_32x32x16(K,Q) -> lane holds S^T[k][q=lane&31], with
//     k = (reg&3)+8*(reg>>2)+4*hi (hi=lane>>5), per 32-kv column block.
//   softmax in-register: exp2 (pre-scaled scores), cvt_pk bf16 pairs.
//   PV B-frag: halves exchange via 16 shfl_xor(.,32)/tile + cndmask — the
//     cross-lane move is ONLY lane<->lane+32 at 32x32 shape (v8's failure
//     was 32 general ds_bpermute at 16x16 shape).
//   PV: O^T = mfma_32x32x16(V^T, P^T); epilogue 1 shfl_xor rowsum + 8
//     ushort4 stores (was 32 scalar).
// Deletes per tile: 32 ds_write_b16 + 4 ds_read_b128 (P round-trip) + the
// mid-tile lgkm serialization; MFMA instr count 32 -> 16 (same FLOPs).
// Ps freed: LDS 51,200 -> 32,768 B -> 4 blocks/CU.
// ---------------------------------------------------------------------------
__global__ __launch_bounds__(256, 4) void attn_fused(
    const u16* __restrict__ Q, const u16* __restrict__ K,
    const u16* __restrict__ Vt, u16* __restrict__ O) {
  __shared__ __align__(16) u16 Kbuf[2][64 * 64];  // [kv row][64 halves] swz
  __shared__ __align__(16) u16 Vbuf[2][64 * 64];  // [d row][64 halves] swz

  const int tid  = threadIdx.x;
  const int lane = tid & 63;
  const int wave = tid >> 6;
  const int q31  = lane & 31;
  const int hi   = lane >> 5;
  const int gid  = blockIdx.x;
  const int bh = ((gid & 7) << 3) | ((gid >> 3) & 7);  // 8 bh per XCD
  const int qb = 15 - (gid >> 6);                      // heavy-first
  const int b = bh >> 4;
  const int h = bh & 15;
  const int q0w = qb * 128 + wave * 32;                // wave's q base

  const u16* Kbh = K + (size_t)bh * S_LEN * HD;
  const u16* Vbh = Vt + (size_t)bh * HD * S_LEN;

  // staging lane constants (unchanged): instr covers 8 rows
  const int srow  = lane >> 3;                  // 0..7
  const int sslot = (lane & 7) ^ srow;          // 0..7 (inverse swizzle)
  const int r0a = wave * 16;
  const int r0b = wave * 16 + 8;

  const int qs = q31 & 7;  // row&7 for frag-read swizzle (32-blocks: R&7 = q31&7)

  // Q fragments: B-operand of mfma(K,Q): q=lane&31, contraction d = hi*8+e
  // per d-step m: chunk slot = m*2+hi
  bf16x8 qf[4];
  {
    const u16* Qrow = Q + ((size_t)bh * S_LEN + q0w + q31) * HD;
#pragma unroll
    for (int m = 0; m < 4; m++) qf[m] = gload16(Qrow + (((m << 1) + hi) << 3));
  }

  f32x16 oacc[2];  // O^T: oacc[db][r] = O[q=q0w+q31][d=db*32+(r&3)+8*(r>>2)+4*hi]
#pragma unroll
  for (int db = 0; db < 2; db++)
#pragma unroll
    for (int r = 0; r < 16; r++) oacc[db][r] = 0.f;
  float lacc = 0.f;  // partial row-sum for q (own half's k-values only)

  auto STAGE = [&](int buf, int kv0) {
    gload_lds16(Kbh + (size_t)(kv0 + r0a + srow) * HD + sslot * 8,
                &Kbuf[buf][r0a * 64]);
    gload_lds16(Kbh + (size_t)(kv0 + r0b + srow) * HD + sslot * 8,
                &Kbuf[buf][r0b * 64]);
    gload_lds16(Vbh + (size_t)(r0a + srow) * S_LEN + kv0 + sslot * 8,
                &Vbuf[buf][r0a * 64]);
    gload_lds16(Vbh + (size_t)(r0b + srow) * S_LEN + kv0 + sslot * 8,
                &Vbuf[buf][r0b * 64]);
  };

  const int T = 2 * qb + 2;  // block covers kv tiles 0..T-1
  int cur = 0;
  STAGE(0, 0);
  WAIT_VM(0);  // Q + first tile resident
  BARRIER();

  for (int t = 0; t < T; t++) {
    const int kv0 = t << 6;
    if (t + 1 < T) STAGE(cur ^ 1, kv0 + 64);

    if (kv0 <= q0w + 31) {  // wave-uniform: tile intersects causal range
      // --- swapped QK^T: sct[cb] = S^T over kv rows [cb*32, cb*32+32) ----
      f32x16 sct[2];
#pragma unroll
      for (int cb = 0; cb < 2; cb++) {
#pragma unroll
        for (int r = 0; r < 16; r++) sct[cb][r] = 0.f;
        const u16* kr = &Kbuf[cur][((cb << 5) + q31) * 64];
#pragma unroll
        for (int m = 0; m < 4; m++) {
          const bf16x8 kf = *(const bf16x8*)(kr + ((((m << 1) + hi) ^ qs) << 3));
          sct[cb] = __builtin_amdgcn_mfma_f32_32x32x16_bf16(kf, qf[m], sct[cb], 0, 0, 0);
        }
      }

      // --- softmax in-register: p = exp2(s) (pre-scaled), pack bf16 ------
      // pk[cb][u] holds k-pair {base,base+1}, base=((2u)&3)+8*(u>>1)+4*hi
      uint32_t pk[2][8];
      const bool diag = (kv0 + 63 > q0w);
      const int qg = q0w + q31;
#pragma unroll
      for (int cb = 0; cb < 2; cb++) {
#pragma unroll
        for (int u = 0; u < 8; u++) {
          float p0 = exp2f(sct[cb][2 * u]);
          float p1 = exp2f(sct[cb][2 * u + 1]);
          if (diag) {
            const int k0 = kv0 + (cb << 5) + ((2 * u) & 3) + 8 * (u >> 1) + 4 * hi;
            if (k0 > qg) p0 = 0.f;
            if (k0 + 1 > qg) p1 = 0.f;
          }
          lacc += p0 + p1;
          pk[cb][u] = cvtpk_bf16(p0, p1);
        }
      }

      // --- PV: B-frag per 16-k block via halves exchange, mfma(V^T,P^T) --
#pragma unroll
      for (int m = 0; m < 4; m++) {
        const int cb = m >> 1;
        const int bb = (m & 1) << 2;  // u base: 0 or 4
        const uint32_t x0 = (uint32_t)__shfl_xor((int)pk[cb][bb + 0], 32);
        const uint32_t x1 = (uint32_t)__shfl_xor((int)pk[cb][bb + 1], 32);
        const uint32_t x2 = (uint32_t)__shfl_xor((int)pk[cb][bb + 2], 32);
        const uint32_t x3 = (uint32_t)__shfl_xor((int)pk[cb][bb + 3], 32);
        union { uint32_t u[4]; bf16x8 v; } P;
        P.u[0] = hi ? x2 : pk[cb][bb + 0];
        P.u[1] = hi ? x3 : pk[cb][bb + 1];
        P.u[2] = hi ? pk[cb][bb + 2] : x0;
        P.u[3] = hi ? pk[cb][bb + 3] : x1;
#pragma unroll
        for (int db = 0; db < 2; db++) {
          const bf16x8 vf = *(const bf16x8*)(
              &Vbuf[cur][((db << 5) + q31) * 64 + ((((m << 1) + hi) ^ qs) << 3)]);
          oacc[db] = __builtin_amdgcn_mfma_f32_32x32x16_bf16(vf, P.v, oacc[db], 0, 0, 0);
        }
      }
    }

    WAIT_VM(0);  // next tile's staging (issued above) has landed
    BARRIER();   // all waves done reading cur; next tile visible to all
    cur ^= 1;
  }

  // epilogue: total row-sum = own half + partner half; normalize; store O^T
  {
    const float l = lacc + __shfl_xor(lacc, 32);
    const float inv = 1.0f / l;
    const size_t row = (size_t)b * S_LEN + q0w + q31;
#pragma unroll
    for (int db = 0; db < 2; db++)
#pragma unroll
      for (int g = 0; g < 4; g++) {
        const int d0 = (db << 5) + (g << 3) + (hi << 2);
        ushort4 o;
        o.x = f2bf(oacc[db][g * 4 + 0] * inv);
        o.y = f2bf(oacc[db][g * 4 + 1] * inv);
        o.z = f2bf(oacc[db][g * 4 + 2] * inv);
        o.w = f2bf(oacc[db][g * 4 + 3] * inv);
        *(ushort4*)(&O[row * EDIM + h * HD + d0]) = o;
      }
  }
}

// ---------------------------------------------------------------------------
extern "C" void kernel_launch(void* const* d_in, const int* in_sizes, int n_in,
                              void* d_out, int out_size, void* d_ws, size_t ws_size,
                              hipStream_t stream) {
  const float* x  = (const float*)d_in[0];
  const float* Wq = (const float*)d_in[1];
  const float* Wk = (const float*)d_in[2];
  const float* Wv = (const float*)d_in[3];
  const float* Wp = (const float*)d_in[4];
  const float* bp = (const float*)d_in[5];
  float* out = (float*)d_out;

  char* ws = (char*)d_ws;
  u16* wqkvT  = (u16*)(ws);              //  6,291,456 B  [3072][1024] bf16
  u16* wprojT = (u16*)(ws + 6291456);    //  2,097,152 B  [1024][1024] bf16
  u16* Qb     = (u16*)(ws + 8388608);    // 16,777,216 B  [B,H,S,D] bf16
  u16* Kb     = (u16*)(ws + 25165824);   // 16,777,216 B  [B,H,S,D] bf16
  u16* Vtb    = (u16*)(ws + 41943040);   // 16,777,216 B  [B,H,D,S] bf16
  u16* xb     = (u16*)(ws + 58720256);   // 16,777,216 B  [B*S][E] bf16
  u16* Ob     = xb;                      // aliases xb (dead after QKV GEMM)

  pack_inputs<<<dim3(9216), dim3(256), 0, stream>>>(x, Wq, Wk, Wv, Wp,
                                                    xb, wqkvT, wprojT);
  gemm128<0><<<dim3(24, 64), dim3(256), 0, stream>>>(
      xb, wqkvT, (const float*)nullptr, Qb, Kb, Vtb, (float*)nullptr, 1024, 3072);
  attn_fused<<<dim3(1024), dim3(256), 0, stream>>>(Qb, Kb, Vtb, Ob);
  gemm128<1><<<dim3(8, 64), dim3(256), 0, stream>>>(
      Ob, wprojT, bp, (u16*)nullptr, (u16*)nullptr, (u16*)nullptr, out, 1024, 1024);
}

// Round 10
// 250.045 us; speedup vs baseline: 1.1016x; 1.0696x over previous
//
#include <hip/hip_runtime.h>
#include <stdint.h>

typedef unsigned short u16;
typedef __attribute__((ext_vector_type(8))) short bf16x8;
typedef __attribute__((ext_vector_type(8))) unsigned short u16x8;
typedef __attribute__((ext_vector_type(4))) float f32x4;
typedef __attribute__((ext_vector_type(16))) float f32x16;

#define S_LEN 2048
#define EDIM 1024
#define NH 16
#define HD 64

static __device__ __forceinline__ u16 f2bf(float f) {
  union { float f; uint32_t u; } v; v.f = f;
  uint32_t r = v.u + 0x7fffu + ((v.u >> 16) & 1u);  // RNE
  return (u16)(r >> 16);
}

// packed f32x2 -> bf16x2 (RNE), low=a high=b (validated v8-v11)
static __device__ __forceinline__ uint32_t cvtpk_bf16(float a, float b) {
  uint32_t r;
  asm("v_cvt_pk_bf16_f32 %0, %1, %2" : "=v"(r) : "v"(a), "v"(b));
  return r;
}

// async global->LDS, 16B per lane; LDS dest = wave-uniform base + lane*16
static __device__ __forceinline__ void gload_lds16(const u16* g, u16* l) {
  __builtin_amdgcn_global_load_lds(
      (const __attribute__((address_space(1))) void*)g,
      (__attribute__((address_space(3))) void*)l, 16, 0, 0);
}

// pinned 16B global load (used for Q prologue only)
static __device__ __forceinline__ bf16x8 gload16(const u16* p) {
  bf16x8 r;
  asm volatile("global_load_dwordx4 %0, %1, off" : "=v"(r) : "v"(p));
  return r;
}

// counted wait + full scheduling fence (rule #18)
#define WAIT_VM(n)                                   \
  do {                                               \
    asm volatile("s_waitcnt vmcnt(" #n ")");         \
    __builtin_amdgcn_sched_barrier(0);               \
  } while (0)

#define BARRIER()                                    \
  do {                                               \
    __builtin_amdgcn_s_barrier();                    \
    __builtin_amdgcn_sched_barrier(0);               \
  } while (0)

// ---------------------------------------------------------------------------
// pack v3: x fp32->bf16 vectorized; W transposes via LDS 64x64 tiles.
// Wq pre-scaled by D^-0.5*log2(e): scores come out of QKV GEMM exp2-ready.
// Blocks: [0,8192) x-convert; [8192,8960) wqkv; [8960,9216) wproj.
// ---------------------------------------------------------------------------
__global__ __launch_bounds__(256) void pack_inputs(
    const float* __restrict__ x, const float* __restrict__ Wq,
    const float* __restrict__ Wk, const float* __restrict__ Wv,
    const float* __restrict__ Wp,
    u16* __restrict__ xb, u16* __restrict__ wqkvT, u16* __restrict__ wprojT) {
  const int blk = blockIdx.x;
  const int tid = threadIdx.x;
  if (blk < 8192) {
    int idx = blk * 256 + tid;  // 2,097,152 float4 groups total
    float4 v = ((const float4*)x)[idx];
    ushort4 o;
    o.x = f2bf(v.x); o.y = f2bf(v.y); o.z = f2bf(v.z); o.w = f2bf(v.w);
    ((ushort4*)xb)[idx] = o;
    return;
  }
  __shared__ u16 tile[64][65];  // +1 pad: gather phase 2-way banked (free)
  const float* src;
  size_t src_rs;   // src row stride (floats)
  u16* dst;        // dst tile base: dst + r*1024 + c
  float wscale = 1.0f;
  if (blk < 8960) {
    int t = blk - 8192;          // 0..767
    int mh = t >> 4;             // 0..47
    int et = t & 15;             // e-tile
    int m = mh >> 4, h = mh & 15;
    const float* W = (m == 0) ? Wq : (m == 1) ? Wk : Wv;
    if (m == 0) wscale = 0.1803368801111204f;  // D^-0.5 * log2(e)
    src = W + ((size_t)(h * EDIM + et * 64)) * HD;
    src_rs = HD;
    dst = wqkvT + (size_t)(m * 1024 + h * 64) * 1024 + et * 64;
  } else {
    int t = blk - 8960;          // 0..255
    int kt = t >> 4, nt = t & 15;
    src = Wp + (size_t)(kt * 64) * 1024 + nt * 64;
    src_rs = 1024;
    dst = wprojT + (size_t)(nt * 64) * 1024 + kt * 64;
  }
  {
    const int rr = tid >> 4;        // 0..15
    const int c4 = (tid & 15) << 2; // 0..60
#pragma unroll
    for (int p = 0; p < 4; p++) {
      const int r = p * 16 + rr;
      float4 v = *(const float4*)(src + (size_t)r * src_rs + c4);
      tile[r][c4 + 0] = f2bf(v.x * wscale);
      tile[r][c4 + 1] = f2bf(v.y * wscale);
      tile[r][c4 + 2] = f2bf(v.z * wscale);
      tile[r][c4 + 3] = f2bf(v.w * wscale);
    }
  }
  __syncthreads();
  {
    const int rr = tid >> 3;        // 0..31
    const int c8 = (tid & 7) << 3;  // 0..56
#pragma unroll
    for (int p = 0; p < 2; p++) {
      const int r = p * 32 + rr;    // out row (= src col)
      u16x8 o;
#pragma unroll
      for (int j = 0; j < 8; j++) o[j] = tile[c8 + j][r];
      *(u16x8*)(dst + (size_t)r * 1024 + c8) = o;
    }
  }
}

// ---------------------------------------------------------------------------
// 128x128-tile bf16 MFMA GEMM, BK=64:  C[M,N] = A[M,K] @ Bt[N,K]^T.
// (unchanged from round 5 — BK=64 + slot-XOR swizzle)
// ---------------------------------------------------------------------------
template <int EPI>
__global__ __launch_bounds__(256) void gemm128(
    const u16* __restrict__ A, const u16* __restrict__ Bt,
    const float* __restrict__ bias,
    u16* __restrict__ o0, u16* __restrict__ o1, u16* __restrict__ o2,
    float* __restrict__ of, int K, int N) {
  __shared__ __align__(16) u16 As[128 * 64];  // 16 KB, linear dest (lds-dma)
  __shared__ __align__(16) u16 Bs[128 * 64];
  const int tid  = threadIdx.x;
  const int lane = tid & 63;
  const int wave = tid >> 6;
  const int wm = wave >> 1;
  const int wn = wave & 1;
  const int col = lane & 15;
  const int quad = lane >> 4;
  const int cs = col & 7;
  const int m0 = blockIdx.y << 7;
  const int n0 = blockIdx.x << 7;

  const int srow  = lane >> 3;
  const int sslot = (lane & 7) ^ srow;
  const u16* gA = A + (size_t)(m0 + (wave << 5) + srow) * K + sslot * 8;
  const u16* gB = Bt + (size_t)(n0 + (wave << 5) + srow) * K + sslot * 8;
  u16* lA = &As[(wave << 5) << 6];
  u16* lB = &Bs[(wave << 5) << 6];

  f32x4 acc[4][4];
#pragma unroll
  for (int i = 0; i < 4; i++)
#pragma unroll
    for (int j = 0; j < 4; j++) acc[i][j] = (f32x4){0.f, 0.f, 0.f, 0.f};

  for (int kk = 0; kk < K; kk += 64) {
    __syncthreads();
#pragma unroll
    for (int i = 0; i < 4; i++) {
      gload_lds16(gA + (size_t)(i * 8) * K + kk, lA + i * 512);
      gload_lds16(gB + (size_t)(i * 8) * K + kk, lB + i * 512);
    }
    __syncthreads();

#pragma unroll
    for (int x = 0; x < 2; x++) {  // k-halves: k = x*32 + quad*8
      bf16x8 af[4], bfr[4];
#pragma unroll
      for (int i = 0; i < 4; i++)
        af[i] = *(const bf16x8*)(
            &As[((wm * 64 + i * 16 + col) << 6) + ((((x << 2) + quad) ^ cs) << 3)]);
#pragma unroll
      for (int j = 0; j < 4; j++)
        bfr[j] = *(const bf16x8*)(
            &Bs[((wn * 64 + j * 16 + col) << 6) + ((((x << 2) + quad) ^ cs) << 3)]);
#pragma unroll
      for (int i = 0; i < 4; i++)
#pragma unroll
        for (int j = 0; j < 4; j++)
          acc[i][j] = __builtin_amdgcn_mfma_f32_16x16x32_bf16(af[i], bfr[j],
                                                              acc[i][j], 0, 0, 0);
    }
  }

#pragma unroll
  for (int i = 0; i < 4; i++) {
#pragma unroll
    for (int j = 0; j < 4; j++) {
      // C/D layout: col=lane&15, row=quad*4+reg  [m89-verified]
      const int rg0 = m0 + wm * 64 + i * 16 + quad * 4;
      const int cg = n0 + wn * 64 + j * 16 + col;
      if (EPI == 0) {
        const int mat = cg >> 10;
        const int rem = cg & 1023;
        const int h = rem >> 6;
        const int d = rem & 63;
        const int b = rg0 >> 11;
        const int s0 = rg0 & 2047;
        if (mat == 2) {
          ushort4 o;
          o.x = f2bf(acc[i][j][0]); o.y = f2bf(acc[i][j][1]);
          o.z = f2bf(acc[i][j][2]); o.w = f2bf(acc[i][j][3]);
          *(ushort4*)(&o2[(((size_t)(b * NH + h) * HD + d) << 11) + s0]) = o;
        } else {
          u16* dst = (mat == 0) ? o0 : o1;
#pragma unroll
          for (int r = 0; r < 4; r++)
            dst[((size_t)((b * NH + h) * S_LEN + s0 + r) << 6) + d] =
                f2bf(acc[i][j][r]);
        }
      } else {
#pragma unroll
        for (int r = 0; r < 4; r++)
          of[(size_t)(rg0 + r) * N + cg] = acc[i][j][r] + bias[cg];
      }
    }
  }
}

// ---------------------------------------------------------------------------
// Fused causal flash attention v12 — v11 compute (32x32 MFMA, in-register P)
// + DEPTH-2 STAGING PIPELINE (T3/T4: tri-buffer, counted vmcnt).
// Ablation evidence: v7/v10/v11 (different VALU/LDS/MFMA mixes) all = 79.2us
// -> critical path is the depth-1 stage->vmcnt(0)->barrier drain (~4.4k of
// ~5.9k cyc/iter). v12 stages tile t+2 at iter t and waits vmcnt(4): only
// tile t+1's 4 loads must have landed; t+2's stay in flight ACROSS the
// barrier. DMA latency budget: ~2 compute phases instead of <1.
// Per-wave vmcnt accounting exact: 4 gload_lds per tile per wave, in-order;
// wait = (t+2<T) ? 4 : 0. LDS 3x16KB = 48KB -> 3 blocks/CU (v11's Ps-free
// 32KB footprint is what makes the third buffer fit).
// ---------------------------------------------------------------------------
__global__ __launch_bounds__(256, 3) void attn_fused(
    const u16* __restrict__ Q, const u16* __restrict__ K,
    const u16* __restrict__ Vt, u16* __restrict__ O) {
  __shared__ __align__(16) u16 Kbuf[3][64 * 64];  // [kv row][64 halves] swz
  __shared__ __align__(16) u16 Vbuf[3][64 * 64];  // [d row][64 halves] swz

  const int tid  = threadIdx.x;
  const int lane = tid & 63;
  const int wave = tid >> 6;
  const int q31  = lane & 31;
  const int hi   = lane >> 5;
  const int gid  = blockIdx.x;
  const int bh = ((gid & 7) << 3) | ((gid >> 3) & 7);  // 8 bh per XCD
  const int qb = 15 - (gid >> 6);                      // heavy-first
  const int b = bh >> 4;
  const int h = bh & 15;
  const int q0w = qb * 128 + wave * 32;                // wave's q base

  const u16* Kbh = K + (size_t)bh * S_LEN * HD;
  const u16* Vbh = Vt + (size_t)bh * HD * S_LEN;

  // staging lane constants: instr covers 8 rows
  const int srow  = lane >> 3;                  // 0..7
  const int sslot = (lane & 7) ^ srow;          // 0..7 (inverse swizzle)
  const int r0a = wave * 16;
  const int r0b = wave * 16 + 8;

  const int qs = q31 & 7;  // row&7 for frag-read swizzle

  // Q fragments: B-operand of mfma(K,Q): q=lane&31, chunk slot = m*2+hi
  bf16x8 qf[4];
  {
    const u16* Qrow = Q + ((size_t)bh * S_LEN + q0w + q31) * HD;
#pragma unroll
    for (int m = 0; m < 4; m++) qf[m] = gload16(Qrow + (((m << 1) + hi) << 3));
  }

  f32x16 oacc[2];  // O^T: oacc[db][r] = O[q][d=db*32+(r&3)+8*(r>>2)+4*hi]
#pragma unroll
  for (int db = 0; db < 2; db++)
#pragma unroll
    for (int r = 0; r < 16; r++) oacc[db][r] = 0.f;
  float lacc = 0.f;  // partial row-sum (own half's k-values)

  auto STAGE = [&](int buf, int kv0) {
    gload_lds16(Kbh + (size_t)(kv0 + r0a + srow) * HD + sslot * 8,
                &Kbuf[buf][r0a * 64]);
    gload_lds16(Kbh + (size_t)(kv0 + r0b + srow) * HD + sslot * 8,
                &Kbuf[buf][r0b * 64]);
    gload_lds16(Vbh + (size_t)(r0a + srow) * S_LEN + kv0 + sslot * 8,
                &Vbuf[buf][r0a * 64]);
    gload_lds16(Vbh + (size_t)(r0b + srow) * S_LEN + kv0 + sslot * 8,
                &Vbuf[buf][r0b * 64]);
  };

  const int T = 2 * qb + 2;  // block covers kv tiles 0..T-1  (T >= 2)
  // prologue: stage tiles 0 and 1; Q loads + tile0 must land, tile1 in flight
  STAGE(0, 0);
  STAGE(1, 64);
  WAIT_VM(4);  // Q(4) + S0(4) done; S1(4) may be outstanding
  BARRIER();

  int cur = 0;   // buffer holding tile t
  int stg = 2;   // buffer to stage tile t+2 into
  for (int t = 0; t < T; t++) {
    const int kv0 = t << 6;
    if (t + 2 < T) STAGE(stg, kv0 + 128);

    if (kv0 <= q0w + 31) {  // wave-uniform: tile intersects causal range
      // --- swapped QK^T: sct[cb] = S^T over kv rows [cb*32, cb*32+32) ----
      f32x16 sct[2];
#pragma unroll
      for (int cb = 0; cb < 2; cb++) {
#pragma unroll
        for (int r = 0; r < 16; r++) sct[cb][r] = 0.f;
        const u16* kr = &Kbuf[cur][((cb << 5) + q31) * 64];
#pragma unroll
        for (int m = 0; m < 4; m++) {
          const bf16x8 kf = *(const bf16x8*)(kr + ((((m << 1) + hi) ^ qs) << 3));
          sct[cb] = __builtin_amdgcn_mfma_f32_32x32x16_bf16(kf, qf[m], sct[cb], 0, 0, 0);
        }
      }

      // --- softmax in-register: p = exp2(s) (pre-scaled), pack bf16 ------
      uint32_t pk[2][8];
      const bool diag = (kv0 + 63 > q0w);
      const int qg = q0w + q31;
#pragma unroll
      for (int cb = 0; cb < 2; cb++) {
#pragma unroll
        for (int u = 0; u < 8; u++) {
          float p0 = exp2f(sct[cb][2 * u]);
          float p1 = exp2f(sct[cb][2 * u + 1]);
          if (diag) {
            const int k0 = kv0 + (cb << 5) + ((2 * u) & 3) + 8 * (u >> 1) + 4 * hi;
            if (k0 > qg) p0 = 0.f;
            if (k0 + 1 > qg) p1 = 0.f;
          }
          lacc += p0 + p1;
          pk[cb][u] = cvtpk_bf16(p0, p1);
        }
      }

      // --- PV: B-frag per 16-k block via halves exchange, mfma(V^T,P^T) --
#pragma unroll
      for (int m = 0; m < 4; m++) {
        const int cb = m >> 1;
        const int bb = (m & 1) << 2;  // u base: 0 or 4
        const uint32_t x0 = (uint32_t)__shfl_xor((int)pk[cb][bb + 0], 32);
        const uint32_t x1 = (uint32_t)__shfl_xor((int)pk[cb][bb + 1], 32);
        const uint32_t x2 = (uint32_t)__shfl_xor((int)pk[cb][bb + 2], 32);
        const uint32_t x3 = (uint32_t)__shfl_xor((int)pk[cb][bb + 3], 32);
        union { uint32_t u[4]; bf16x8 v; } P;
        P.u[0] = hi ? x2 : pk[cb][bb + 0];
        P.u[1] = hi ? x3 : pk[cb][bb + 1];
        P.u[2] = hi ? pk[cb][bb + 2] : x0;
        P.u[3] = hi ? pk[cb][bb + 3] : x1;
#pragma unroll
        for (int db = 0; db < 2; db++) {
          const bf16x8 vf = *(const bf16x8*)(
              &Vbuf[cur][((db << 5) + q31) * 64 + ((((m << 1) + hi) ^ qs) << 3)]);
          oacc[db] = __builtin_amdgcn_mfma_f32_32x32x16_bf16(vf, P.v, oacc[db], 0, 0, 0);
        }
      }
    }

    // tile t+1 ready; tile t+2's loads stay in flight across the barrier
    if (t + 2 < T) { WAIT_VM(4); } else { WAIT_VM(0); }
    BARRIER();
    cur = (cur == 2) ? 0 : cur + 1;
    stg = (stg == 2) ? 0 : stg + 1;
  }

  // epilogue: total row-sum = own half + partner half; normalize; store O^T
  {
    const float l = lacc + __shfl_xor(lacc, 32);
    const float inv = 1.0f / l;
    const size_t row = (size_t)b * S_LEN + q0w + q31;
#pragma unroll
    for (int db = 0; db < 2; db++)
#pragma unroll
      for (int g = 0; g < 4; g++) {
        const int d0 = (db << 5) + (g << 3) + (hi << 2);
        ushort4 o;
        o.x = f2bf(oacc[db][g * 4 + 0] * inv);
        o.y = f2bf(oacc[db][g * 4 + 1] * inv);
        o.z = f2bf(oacc[db][g * 4 + 2] * inv);
        o.w = f2bf(oacc[db][g * 4 + 3] * inv);
        *(ushort4*)(&O[row * EDIM + h * HD + d0]) = o;
      }
  }
}

// ---------------------------------------------------------------------------
extern "C" void kernel_launch(void* const* d_in, const int* in_sizes, int n_in,
                              void* d_out, int out_size, void* d_ws, size_t ws_size,
                              hipStream_t stream) {
  const float* x  = (const float*)d_in[0];
  const float* Wq = (const float*)d_in[1];
  const float* Wk = (const float*)d_in[2];
  const float* Wv = (const float*)d_in[3];
  const float* Wp = (const float*)d_in[4];
  const float* bp = (const float*)d_in[5];
  float* out = (float*)d_out;

  char* ws = (char*)d_ws;
  u16* wqkvT  = (u16*)(ws);              //  6,291,456 B  [3072][1024] bf16
  u16* wprojT = (u16*)(ws + 6291456);    //  2,097,152 B  [1024][1024] bf16
  u16* Qb     = (u16*)(ws + 8388608);    // 16,777,216 B  [B,H,S,D] bf16
  u16* Kb     = (u16*)(ws + 25165824);   // 16,777,216 B  [B,H,S,D] bf16
  u16* Vtb    = (u16*)(ws + 41943040);   // 16,777,216 B  [B,H,D,S] bf16
  u16* xb     = (u16*)(ws + 58720256);   // 16,777,216 B  [B*S][E] bf16
  u16* Ob     = xb;                      // aliases xb (dead after QKV GEMM)

  pack_inputs<<<dim3(9216), dim3(256), 0, stream>>>(x, Wq, Wk, Wv, Wp,
                                                    xb, wqkvT, wprojT);
  gemm128<0><<<dim3(24, 64), dim3(256), 0, stream>>>(
      xb, wqkvT, (const float*)nullptr, Qb, Kb, Vtb, (float*)nullptr, 1024, 3072);
  attn_fused<<<dim3(1024), dim3(256), 0, stream>>>(Qb, Kb, Vtb, Ob);
  gemm128<1><<<dim3(8, 64), dim3(256), 0, stream>>>(
      Ob, wprojT, bp, (u16*)nullptr, (u16*)nullptr, (u16*)nullptr, out, 1024, 1024);
}